// Round 6
// baseline (90.385 us; speedup 1.0000x reference)
//
#include <hip/hip_runtime.h>

#define G_ 20000
#define W_ 8
#define K_ 16
#define T_ 1500
#define B_ 256
#define D_ 2
#define GPB 2        // groups per block
#define BPT 2        // batch rows per thread (consecutive -> float2 gathers)
#define TPB 128      // threads per block = B_/BPT; 2 waves
#define PSTRIDE 308  // floats per packed group record (1232 B, 16B-aligned)

typedef float v2f __attribute__((ext_vector_type(2)));

// ---------- prep kernels ----------

// feat (B,T) -> featT (T,B): gathers in main kernel become lane-coalesced.
__global__ void transpose_feat(const float* __restrict__ feat,
                               float* __restrict__ featT) {
    __shared__ float tile[32][33];
    int t0 = blockIdx.x * 32;
    int b0 = blockIdx.y * 32;
    int tx = threadIdx.x, ty = threadIdx.y;  // block (32,8)
    #pragma unroll
    for (int i = 0; i < 32; i += 8) {
        int bb = b0 + ty + i, tt = t0 + tx;
        if (bb < B_ && tt < T_) tile[ty + i][tx] = feat[bb * T_ + tt];
    }
    __syncthreads();
    #pragma unroll
    for (int i = 0; i < 32; i += 8) {
        int tt = t0 + ty + i, bb = b0 + tx;
        if (tt < T_ && bb < B_) featT[tt * B_ + bb] = tile[tx][ty + i];
    }
}

// One contiguous record per group; SELU constants folded; indices first
// (premultiplied by B) so the gather s_loads issue earliest.
// Layout (floats):
//   [0,16)    tf_idx*B_ (int bits)
//   [16,144)  W1t[k][w]  * log2e
//   [144,152) b1         * log2e
//   [152,280) Wmt[d][w][v] * scale*log2e
//   [280,296) bm[d][v]   * log2e
//   [296,304) Wf         * scale
//   [304]     bf
//   [305,308) pad
__global__ void pack_weights(const int*   __restrict__ tf_idx,
                             const float* __restrict__ W1,
                             const float* __restrict__ b1,
                             const float* __restrict__ Wm,
                             const float* __restrict__ bm,
                             const float* __restrict__ Wf,
                             const float* __restrict__ bf,
                             float* __restrict__ pack) {
    long i = (long)blockIdx.x * blockDim.x + threadIdx.x;
    if (i >= (long)G_ * PSTRIDE) return;
    int g = (int)(i / PSTRIDE);
    int j = (int)(i - (long)g * PSTRIDE);
    const float LOG2E = 1.44269504088896340736f;
    const float SCALE = 1.0507009873554805f;
    float v;
    if (j < 16) {
        int t = tf_idx[g * K_ + j];
        v = __int_as_float(t * B_);
    } else if (j < 144) {
        int r = j - 16, k = r >> 3, w = r & 7;
        v = LOG2E * W1[((long)g * W_ + w) * K_ + k];
    } else if (j < 152) {
        v = LOG2E * b1[g * W_ + (j - 144)];
    } else if (j < 280) {
        int r = j - 152, d = r >> 6, w = (r >> 3) & 7, vv = r & 7;
        v = SCALE * LOG2E * Wm[(((long)d * G_ + g) * W_ + vv) * W_ + w];
    } else if (j < 296) {
        int r = j - 280, d = r >> 3, vv = r & 7;
        v = LOG2E * bm[((long)d * G_ + g) * W_ + vv];
    } else if (j < 304) {
        v = SCALE * Wf[g * W_ + (j - 296)];
    } else if (j == 304) {
        v = bf[g];
    } else {
        v = 0.0f;
    }
    pack[i] = v;
}

// outT (G,B) -> out (B,G), both sides coalesced via LDS tile.
__global__ void transpose_out(const float* __restrict__ in,
                              float* __restrict__ outp) {
    __shared__ float tile[32][33];
    int g0 = blockIdx.x * 32;
    int b0 = blockIdx.y * 32;
    int tx = threadIdx.x, ty = threadIdx.y;  // block (32,8)
    #pragma unroll
    for (int i = 0; i < 32; i += 8)
        tile[ty + i][tx] = in[(size_t)(g0 + ty + i) * B_ + b0 + tx];
    __syncthreads();
    #pragma unroll
    for (int i = 0; i < 32; i += 8)
        outp[(size_t)(b0 + ty + i) * G_ + g0 + tx] = tile[tx][ty + i];
}

// ---------- main kernel ----------

// input u = log2e * z ; returns selu(z)/scale (scale folded into consumer).
// Branch-free 5-op form: max-path and min-path are mutually exclusive.
__device__ __forceinline__ float selu_u(float u) {
    const float ALPHA = 1.6732632423543772f;
    const float LN2   = 0.6931471805599453f;
    float e  = __builtin_amdgcn_exp2f(u);            // v_exp_f32
    float m  = fmaf(ALPHA, e, -ALPHA);               // alpha*(e^z - 1)
    return fmaf(fmaxf(u, 0.0f), LN2, fminf(m, 0.0f));
}

// 128 threads (2 waves), thread owns batch rows {2*tid, 2*tid+1} for GPB
// consecutive groups. Weight record uniform -> s_load broadcast.
// Stores go to outT(G,B): per g, 128 threads x float2 = 1KB contiguous
// full lines (fixes the 4.5x write amplification of out(B,G) direct).
__global__ __launch_bounds__(TPB, 6) void decoder_packed2(
    const float* __restrict__ featT,   // (T,B)
    const float* __restrict__ pack,    // (G,PSTRIDE)
    float* __restrict__ outT)          // (G,B)
{
    const int tid = threadIdx.x;
    const int b0  = BPT * tid;
    const int g0  = blockIdx.x * GPB;
    const float* fb = featT + b0;
    float res[BPT][GPB];

    #pragma unroll
    for (int gi = 0; gi < GPB; ++gi) {
        const int g = g0 + gi;
        const float* P    = pack + (long)g * PSTRIDE;
        const int*   idxp = (const int*)P;            // [0,16): t*B_
        const v2f*   Pw1  = (const v2f*)(P + 16);     // W1t pairs
        const v2f*   Pb1  = (const v2f*)(P + 144);
        const v2f*   Pwm  = (const v2f*)(P + 152);
        const v2f*   Pbm  = (const v2f*)(P + 280);

        // coalesced float2 gathers: both batch rows in one dwordx2
        float2 xg[K_];
        #pragma unroll
        for (int k = 0; k < K_; ++k)
            xg[k] = *(const float2*)(fb + idxp[k]);

        // layer 1: pk-acc over output pairs, one acc set per batch row
        v2f a0[4], a1[4];
        #pragma unroll
        for (int j = 0; j < 4; ++j) { a0[j] = Pb1[j]; a1[j] = Pb1[j]; }
        #pragma unroll
        for (int k = 0; k < K_; ++k) {
            float x0 = xg[k].x, x1 = xg[k].y;
            #pragma unroll
            for (int j = 0; j < 4; ++j) {
                v2f wv = Pw1[4 * k + j];
                a0[j] += wv * x0;
                a1[j] += wv * x1;
            }
        }
        float q0[W_], q1[W_];
        #pragma unroll
        for (int j = 0; j < 4; ++j) {
            q0[2*j] = selu_u(a0[j].x); q0[2*j+1] = selu_u(a0[j].y);
            q1[2*j] = selu_u(a1[j].x); q1[2*j+1] = selu_u(a1[j].y);
        }

        // mid layers
        #pragma unroll
        for (int d = 0; d < D_; ++d) {
            v2f m0[4], m1[4];
            #pragma unroll
            for (int j = 0; j < 4; ++j) { m0[j] = Pbm[4*d+j]; m1[j] = Pbm[4*d+j]; }
            #pragma unroll
            for (int w = 0; w < W_; ++w) {
                float h0 = q0[w], h1 = q1[w];
                #pragma unroll
                for (int j = 0; j < 4; ++j) {
                    v2f wv = Pwm[(d * W_ + w) * 4 + j];
                    m0[j] += wv * h0;
                    m1[j] += wv * h1;
                }
            }
            #pragma unroll
            for (int j = 0; j < 4; ++j) {
                q0[2*j] = selu_u(m0[j].x); q0[2*j+1] = selu_u(m0[j].y);
                q1[2*j] = selu_u(m1[j].x); q1[2*j+1] = selu_u(m1[j].y);
            }
        }

        // final dot
        float acc0 = P[304], acc1 = P[304];
        #pragma unroll
        for (int w = 0; w < W_; ++w) {
            float wf = P[296 + w];
            acc0 = fmaf(q0[w], wf, acc0);
            acc1 = fmaf(q1[w], wf, acc1);
        }
        res[0][gi] = acc0;
        res[1][gi] = acc1;
    }

    // full-line coalesced stores to outT(G,B)
    #pragma unroll
    for (int gi = 0; gi < GPB; ++gi)
        *(float2*)(outT + (size_t)(g0 + gi) * B_ + b0) =
            make_float2(res[0][gi], res[1][gi]);
}

// ---------- fallbacks (small workspace) ----------
#define FGPB 4
__device__ __forceinline__ float selu_f(float x) {
    const float scale = 1.0507009873554805f;
    const float sa    = 1.7580993408473766f;
    float e   = __expf(x);
    float neg = fmaf(sa, e, -sa);
    return x > 0.0f ? scale * x : neg;
}
template<bool TRANSPOSED>
__global__ __launch_bounds__(256) void decoder_kernel(
    const float* __restrict__ featsrc, const int* __restrict__ tf_idx,
    const float* __restrict__ W1, const float* __restrict__ b1,
    const float* __restrict__ Wm, const float* __restrict__ bm,
    const float* __restrict__ Wf, const float* __restrict__ bf,
    float* __restrict__ out)
{
    const int b  = threadIdx.x;
    const int g0 = blockIdx.x * FGPB;
    float res[FGPB];
    #pragma unroll
    for (int gi = 0; gi < FGPB; ++gi) {
        const int g = g0 + gi;
        float xg[K_];
        #pragma unroll
        for (int k = 0; k < K_; ++k) {
            int t = tf_idx[g * K_ + k];
            xg[k] = TRANSPOSED ? featsrc[t * B_ + b] : featsrc[b * T_ + t];
        }
        float h[W_];
        #pragma unroll
        for (int w = 0; w < W_; ++w) {
            float acc = b1[g * W_ + w];
            #pragma unroll
            for (int k = 0; k < K_; ++k)
                acc = fmaf(xg[k], W1[(g * W_ + w) * K_ + k], acc);
            h[w] = selu_f(acc);
        }
        #pragma unroll
        for (int d = 0; d < D_; ++d) {
            const float* wmd = Wm + ((size_t)d * G_ + g) * (W_ * W_);
            const float* bmd = bm + ((size_t)d * G_ + g) * W_;
            float h2[W_];
            #pragma unroll
            for (int v = 0; v < W_; ++v) {
                float acc = bmd[v];
                #pragma unroll
                for (int w = 0; w < W_; ++w)
                    acc = fmaf(h[w], wmd[v * W_ + w], acc);
                h2[v] = selu_f(acc);
            }
            #pragma unroll
            for (int w = 0; w < W_; ++w) h[w] = h2[w];
        }
        float acc = bf[g];
        #pragma unroll
        for (int w = 0; w < W_; ++w)
            acc = fmaf(h[w], Wf[g * W_ + w], acc);
        res[gi] = acc;
    }
    float4* o = (float4*)(out + (size_t)b * G_ + g0);
    o[0] = make_float4(res[0], res[1], res[2], res[3]);
}

extern "C" void kernel_launch(void* const* d_in, const int* in_sizes, int n_in,
                              void* d_out, int out_size, void* d_ws, size_t ws_size,
                              hipStream_t stream) {
    const float* feat   = (const float*)d_in[0];
    const int*   tf_idx = (const int*)  d_in[1];
    const float* W1     = (const float*)d_in[2];
    const float* b1     = (const float*)d_in[3];
    const float* Wm     = (const float*)d_in[4];
    const float* bm     = (const float*)d_in[5];
    const float* Wf     = (const float*)d_in[6];
    const float* bf     = (const float*)d_in[7];
    float* out = (float*)d_out;

    const size_t featT_b = (size_t)T_ * B_ * sizeof(float);        // 1.536 MB
    const size_t pack_b  = (size_t)G_ * PSTRIDE * sizeof(float);   // 24.64 MB
    const size_t outT_b  = (size_t)G_ * B_ * sizeof(float);        // 20.48 MB

    if (ws_size >= featT_b + pack_b + outT_b) {
        float* featT = (float*)d_ws;
        float* packp = (float*)((char*)d_ws + featT_b);
        float* outT  = (float*)((char*)d_ws + featT_b + pack_b);

        dim3 tgrid((T_ + 31) / 32, (B_ + 31) / 32);
        hipLaunchKernelGGL(transpose_feat, tgrid, dim3(32, 8), 0, stream, feat, featT);

        long np = (long)G_ * PSTRIDE;
        hipLaunchKernelGGL(pack_weights, dim3((np + 255) / 256), dim3(256), 0,
                           stream, tf_idx, W1, b1, Wm, bm, Wf, bf, packp);

        hipLaunchKernelGGL(decoder_packed2, dim3(G_ / GPB), dim3(TPB), 0,
                           stream, featT, packp, outT);

        hipLaunchKernelGGL(transpose_out, dim3(G_ / 32, B_ / 32), dim3(32, 8), 0,
                           stream, outT, out);
    } else if (ws_size >= featT_b) {
        float* featT = (float*)d_ws;
        dim3 tgrid((T_ + 31) / 32, (B_ + 31) / 32);
        hipLaunchKernelGGL(transpose_feat, tgrid, dim3(32, 8), 0, stream, feat, featT);
        hipLaunchKernelGGL((decoder_kernel<true>), dim3(G_ / FGPB), dim3(B_), 0,
                           stream, featT, tf_idx, W1, b1, Wm, bm, Wf, bf, out);
    } else {
        hipLaunchKernelGGL((decoder_kernel<false>), dim3(G_ / FGPB), dim3(B_), 0,
                           stream, feat, tf_idx, W1, b1, Wm, bm, Wf, bf, out);
    }
}

// Round 7
// 80.788 us; speedup vs baseline: 1.1188x; 1.1188x over previous
//
#include <hip/hip_runtime.h>

#define G_ 20000
#define W_ 8
#define K_ 16
#define T_ 1500
#define B_ 256
#define D_ 2
#define BPT 2        // batch rows per thread (consecutive -> float2 gathers)
#define TPB 128      // threads per block = B_/BPT; 2 waves; 1 group per block
#define PSTRIDE 308  // floats per packed group record (1232 B, 16B-aligned)

// transpose_feat tiles: ceil(1500/32)=47 x 256/32=8
#define TF_TX 47
#define TF_BLOCKS (TF_TX * 8)

typedef float v2f __attribute__((ext_vector_type(2)));

// ---------- fused prep kernel ----------
// blocks [0, TF_BLOCKS): feat (B,T) -> featT (T,B)
// blocks [TF_BLOCKS, TF_BLOCKS+G_): pack ONE group record each (no int div).
// Record layout (floats):
//   [0,16)    tf_idx*B_ (int bits)
//   [16,144)  W1t[k][w]   * log2e
//   [144,152) b1          * log2e
//   [152,280) Wmt[d][w][v]* scale*log2e
//   [280,296) bm[d][v]    * log2e
//   [296,304) Wf          * scale
//   [304]     bf ; [305,308) pad
__global__ __launch_bounds__(256) void prep_kernel(
    const float* __restrict__ feat,
    float* __restrict__ featT,
    const int*   __restrict__ tf_idx,
    const float* __restrict__ W1,
    const float* __restrict__ b1,
    const float* __restrict__ Wm,
    const float* __restrict__ bm,
    const float* __restrict__ Wf,
    const float* __restrict__ bf,
    float* __restrict__ pack)
{
    const int bid = blockIdx.x;
    const int tid = threadIdx.x;
    if (bid < TF_BLOCKS) {
        __shared__ float tile[32][33];
        int t0 = (bid % TF_TX) * 32;
        int b0 = (bid / TF_TX) * 32;
        int tx = tid & 31, ty = tid >> 5;      // (32,8)
        #pragma unroll
        for (int i = 0; i < 32; i += 8) {
            int bb = b0 + ty + i, tt = t0 + tx;
            if (tt < T_) tile[ty + i][tx] = feat[bb * T_ + tt];
        }
        __syncthreads();
        #pragma unroll
        for (int i = 0; i < 32; i += 8) {
            int tt = t0 + ty + i, bb = b0 + tx;
            if (tt < T_) featT[tt * B_ + bb] = tile[tx][ty + i];
        }
        return;
    }
    const int g = bid - TF_BLOCKS;
    const float LOG2E = 1.44269504088896340736f;
    const float SCALE = 1.0507009873554805f;
    float* rec = pack + (long)g * PSTRIDE;
    for (int j = tid; j < PSTRIDE; j += 256) {
        float v;
        if (j < 16) {
            v = __int_as_float(tf_idx[g * K_ + j] * B_);
        } else if (j < 144) {
            int r = j - 16, k = r >> 3, w = r & 7;
            v = LOG2E * W1[((long)g * W_ + w) * K_ + k];
        } else if (j < 152) {
            v = LOG2E * b1[g * W_ + (j - 144)];
        } else if (j < 280) {
            int r = j - 152, d = r >> 6, w = (r >> 3) & 7, vv = r & 7;
            v = SCALE * LOG2E * Wm[(((long)d * G_ + g) * W_ + vv) * W_ + w];
        } else if (j < 296) {
            int r = j - 280, d = r >> 3, vv = r & 7;
            v = LOG2E * bm[((long)d * G_ + g) * W_ + vv];
        } else if (j < 304) {
            v = SCALE * Wf[g * W_ + (j - 296)];
        } else if (j == 304) {
            v = bf[g];
        } else {
            v = 0.0f;
        }
        rec[j] = v;
    }
}

// outT (G,B) -> out (B,G), both sides coalesced via LDS tile.
__global__ void transpose_out(const float* __restrict__ in,
                              float* __restrict__ outp) {
    __shared__ float tile[32][33];
    int g0 = blockIdx.x * 32;
    int b0 = blockIdx.y * 32;
    int tx = threadIdx.x, ty = threadIdx.y;  // block (32,8)
    #pragma unroll
    for (int i = 0; i < 32; i += 8)
        tile[ty + i][tx] = in[(size_t)(g0 + ty + i) * B_ + b0 + tx];
    __syncthreads();
    #pragma unroll
    for (int i = 0; i < 32; i += 8)
        outp[(size_t)(b0 + ty + i) * G_ + g0 + tx] = tile[tx][ty + i];
}

// ---------- main kernel ----------

// u = log2e*z pair; returns selu(z)/scale pair (scale folded into consumer).
__device__ __forceinline__ v2f selu2(v2f u) {
    const float ALPHA = 1.6732632423543772f;
    const float LN2   = 0.6931471805599453f;
    v2f e;
    e.x = __builtin_amdgcn_exp2f(u.x);
    e.y = __builtin_amdgcn_exp2f(u.y);
    v2f m = e * ALPHA - ALPHA;               // pk_fma candidate
    v2f r;
    r.x = fmaf(fmaxf(u.x, 0.0f), LN2, fminf(m.x, 0.0f));
    r.y = fmaf(fmaxf(u.y, 0.0f), LN2, fminf(m.y, 0.0f));
    return r;
}

// 128 threads (2 waves), 1 group per block, thread owns batch rows
// {2*tid, 2*tid+1}. Grid = 20000 blocks = 40000 waves (4.9 occupancy fills;
// round 6's GPB=2 gave only 2.44 -> 56% occupancy, tail-limited).
__global__ __launch_bounds__(TPB, 8) void decoder_packed3(
    const float* __restrict__ featT,   // (T,B)
    const float* __restrict__ pack,    // (G,PSTRIDE)
    float* __restrict__ outT)          // (G,B)
{
    const int tid = threadIdx.x;
    const int b0  = BPT * tid;
    const int g   = blockIdx.x;
    const float* fb = featT + b0;

    const float* P    = pack + (long)g * PSTRIDE;
    const int*   idxp = (const int*)P;            // [0,16): t*B_
    const v2f*   Pw1  = (const v2f*)(P + 16);
    const v2f*   Pb1  = (const v2f*)(P + 144);
    const v2f*   Pwm  = (const v2f*)(P + 152);
    const v2f*   Pbm  = (const v2f*)(P + 280);
    const v2f*   Pwf  = (const v2f*)(P + 296);

    // coalesced float2 gathers: both batch rows in one dwordx2
    float2 xg[K_];
    #pragma unroll
    for (int k = 0; k < K_; ++k)
        xg[k] = *(const float2*)(fb + idxp[k]);

    // layer 1: pk-acc over output pairs, one acc set per batch row
    v2f a0[4], a1[4];
    #pragma unroll
    for (int j = 0; j < 4; ++j) { a0[j] = Pb1[j]; a1[j] = Pb1[j]; }
    #pragma unroll
    for (int k = 0; k < K_; ++k) {
        float x0 = xg[k].x, x1 = xg[k].y;
        #pragma unroll
        for (int j = 0; j < 4; ++j) {
            v2f wv = Pw1[4 * k + j];
            a0[j] += wv * x0;
            a1[j] += wv * x1;
        }
    }
    v2f q0[4], q1[4];
    #pragma unroll
    for (int j = 0; j < 4; ++j) { q0[j] = selu2(a0[j]); q1[j] = selu2(a1[j]); }

    // mid layers: pairs over output v; broadcast q components
    #pragma unroll
    for (int d = 0; d < D_; ++d) {
        v2f m0[4], m1[4];
        #pragma unroll
        for (int j = 0; j < 4; ++j) { m0[j] = Pbm[4*d+j]; m1[j] = Pbm[4*d+j]; }
        #pragma unroll
        for (int w = 0; w < W_; ++w) {
            float h0 = (w & 1) ? q0[w >> 1].y : q0[w >> 1].x;
            float h1 = (w & 1) ? q1[w >> 1].y : q1[w >> 1].x;
            #pragma unroll
            for (int j = 0; j < 4; ++j) {
                v2f wv = Pwm[(d * W_ + w) * 4 + j];
                m0[j] += wv * h0;
                m1[j] += wv * h1;
            }
        }
        #pragma unroll
        for (int j = 0; j < 4; ++j) { q0[j] = selu2(m0[j]); q1[j] = selu2(m1[j]); }
    }

    // final dot: packed partial sums + horizontal add
    v2f s0 = Pwf[0] * q0[0], s1 = Pwf[0] * q1[0];
    #pragma unroll
    for (int j = 1; j < 4; ++j) {
        s0 += Pwf[j] * q0[j];
        s1 += Pwf[j] * q1[j];
    }
    float bfv  = P[304];
    float acc0 = s0.x + s0.y + bfv;
    float acc1 = s1.x + s1.y + bfv;

    // full-line coalesced store: 128 threads x 8B = 1KB contiguous per group
    *(float2*)(outT + (size_t)g * B_ + b0) = make_float2(acc0, acc1);
}

// ---------- fallbacks (small workspace) ----------
#define FGPB 4
__device__ __forceinline__ float selu_f(float x) {
    const float scale = 1.0507009873554805f;
    const float sa    = 1.7580993408473766f;
    float e   = __expf(x);
    float neg = fmaf(sa, e, -sa);
    return x > 0.0f ? scale * x : neg;
}
template<bool TRANSPOSED>
__global__ __launch_bounds__(256) void decoder_kernel(
    const float* __restrict__ featsrc, const int* __restrict__ tf_idx,
    const float* __restrict__ W1, const float* __restrict__ b1,
    const float* __restrict__ Wm, const float* __restrict__ bm,
    const float* __restrict__ Wf, const float* __restrict__ bf,
    float* __restrict__ out)
{
    const int b  = threadIdx.x;
    const int g0 = blockIdx.x * FGPB;
    float res[FGPB];
    #pragma unroll
    for (int gi = 0; gi < FGPB; ++gi) {
        const int g = g0 + gi;
        float xg[K_];
        #pragma unroll
        for (int k = 0; k < K_; ++k) {
            int t = tf_idx[g * K_ + k];
            xg[k] = TRANSPOSED ? featsrc[t * B_ + b] : featsrc[b * T_ + t];
        }
        float h[W_];
        #pragma unroll
        for (int w = 0; w < W_; ++w) {
            float acc = b1[g * W_ + w];
            #pragma unroll
            for (int k = 0; k < K_; ++k)
                acc = fmaf(xg[k], W1[(g * W_ + w) * K_ + k], acc);
            h[w] = selu_f(acc);
        }
        #pragma unroll
        for (int d = 0; d < D_; ++d) {
            const float* wmd = Wm + ((size_t)d * G_ + g) * (W_ * W_);
            const float* bmd = bm + ((size_t)d * G_ + g) * W_;
            float h2[W_];
            #pragma unroll
            for (int v = 0; v < W_; ++v) {
                float acc = bmd[v];
                #pragma unroll
                for (int w = 0; w < W_; ++w)
                    acc = fmaf(h[w], wmd[v * W_ + w], acc);
                h2[v] = selu_f(acc);
            }
            #pragma unroll
            for (int w = 0; w < W_; ++w) h[w] = h2[w];
        }
        float acc = bf[g];
        #pragma unroll
        for (int w = 0; w < W_; ++w)
            acc = fmaf(h[w], Wf[g * W_ + w], acc);
        res[gi] = acc;
    }
    float4* o = (float4*)(out + (size_t)b * G_ + g0);
    o[0] = make_float4(res[0], res[1], res[2], res[3]);
}

extern "C" void kernel_launch(void* const* d_in, const int* in_sizes, int n_in,
                              void* d_out, int out_size, void* d_ws, size_t ws_size,
                              hipStream_t stream) {
    const float* feat   = (const float*)d_in[0];
    const int*   tf_idx = (const int*)  d_in[1];
    const float* W1     = (const float*)d_in[2];
    const float* b1     = (const float*)d_in[3];
    const float* Wm     = (const float*)d_in[4];
    const float* bm     = (const float*)d_in[5];
    const float* Wf     = (const float*)d_in[6];
    const float* bf     = (const float*)d_in[7];
    float* out = (float*)d_out;

    const size_t featT_b = (size_t)T_ * B_ * sizeof(float);        // 1.536 MB
    const size_t pack_b  = (size_t)G_ * PSTRIDE * sizeof(float);   // 24.64 MB
    const size_t outT_b  = (size_t)G_ * B_ * sizeof(float);        // 20.48 MB

    if (ws_size >= featT_b + pack_b + outT_b) {
        float* featT = (float*)d_ws;
        float* packp = (float*)((char*)d_ws + featT_b);
        float* outT  = (float*)((char*)d_ws + featT_b + pack_b);

        hipLaunchKernelGGL(prep_kernel, dim3(TF_BLOCKS + G_), dim3(256), 0,
                           stream, feat, featT, tf_idx, W1, b1, Wm, bm, Wf, bf,
                           packp);

        hipLaunchKernelGGL(decoder_packed3, dim3(G_), dim3(TPB), 0,
                           stream, featT, packp, outT);

        hipLaunchKernelGGL(transpose_out, dim3(G_ / 32, B_ / 32), dim3(32, 8), 0,
                           stream, outT, out);
    } else if (ws_size >= featT_b) {
        float* featT = (float*)d_ws;
        dim3 tgrid((T_ + 31) / 32, (B_ + 31) / 32);
        hipLaunchKernelGGL(prep_kernel, dim3(TF_BLOCKS), dim3(256), 0,
                           stream, feat, featT, tf_idx, W1, b1, Wm, bm, Wf, bf,
                           featT /*unused pack*/);
        hipLaunchKernelGGL((decoder_kernel<true>), dim3(G_ / FGPB), dim3(B_), 0,
                           stream, featT, tf_idx, W1, b1, Wm, bm, Wf, bf, out);
    } else {
        hipLaunchKernelGGL((decoder_kernel<false>), dim3(G_ / FGPB), dim3(B_), 0,
                           stream, feat, tf_idx, W1, b1, Wm, bm, Wf, bf, out);
    }
}